// Round 1
// baseline (1428.053 us; speedup 1.0000x reference)
//
#include <hip/hip_runtime.h>

#define D 128
#define N_DST 100000
#define N_EDGES 640000
#define ROWS 16

// Phase 1: scatter-add source features into per-destination sums (stored in d_out)
// and count degrees. One thread per (edge, 4-feature chunk): 32 threads/edge.
__global__ __launch_bounds__(256) void sage_scatter(
    const float* __restrict__ h_src,
    const int* __restrict__ src_idx,
    const int* __restrict__ dst_idx,
    float* __restrict__ sum_out,   // [N_DST, D], pre-zeroed
    float* __restrict__ deg)       // [N_DST], pre-zeroed
{
    int tid = blockIdx.x * blockDim.x + threadIdx.x;
    int e = tid >> 5;
    int c = tid & 31;
    if (e >= N_EDGES) return;
    int s = src_idx[e];
    int d = dst_idx[e];
    float4 v = ((const float4*)(h_src + (size_t)s * D))[c];
    float* dst = sum_out + (size_t)d * D + c * 4;
    atomicAdd(dst + 0, v.x);
    atomicAdd(dst + 1, v.y);
    atomicAdd(dst + 2, v.z);
    atomicAdd(dst + 3, v.w);
    if (c == 0) atomicAdd(deg + d, 1.0f);
}

// Phase 2: out[i,:] = b + h_dst[i,:] @ W[0:128,:] + (sum[i,:]/max(deg,1)) @ W[128:256,:]
// One block = 16 rows x 128 cols. Reads its rows' sums from `out` into LDS,
// then overwrites those same rows with the projection (block owns its rows).
__global__ __launch_bounds__(256) void sage_gemm(
    const float* __restrict__ h_dst,
    const float* __restrict__ W,     // [256, 128]
    const float* __restrict__ b,     // [128]
    const float* __restrict__ deg,   // [N_DST]
    float* __restrict__ out)         // in: neighbor sums; out: result
{
    __shared__ float sh_hd[ROWS][D];
    __shared__ float sh_hn[ROWS][D];

    const int row0 = blockIdx.x * ROWS;
    const int tid = threadIdx.x;

    // Cooperative tile load: ROWS*D/4 = 512 float4 per tile, 2 per thread.
    for (int i = tid; i < ROWS * D / 4; i += 256) {
        int r = (i * 4) / D;
        ((float4*)sh_hd)[i] = ((const float4*)(h_dst + (size_t)row0 * D))[i];
        float4 sv = ((const float4*)(out + (size_t)row0 * D))[i];
        float inv = 1.0f / fmaxf(deg[row0 + r], 1.0f);
        sv.x *= inv; sv.y *= inv; sv.z *= inv; sv.w *= inv;
        ((float4*)sh_hn)[i] = sv;
    }
    __syncthreads();

    const int j  = tid & 127;   // output column
    const int rg = tid >> 7;    // row group: 0 or 1 (8 rows each)

    float acc[8];
    const float bj = b[j];
#pragma unroll
    for (int r = 0; r < 8; r++) acc[r] = bj;

    for (int k = 0; k < D; k++) {
        float w1 = W[k * D + j];
        float w2 = W[(D + k) * D + j];
#pragma unroll
        for (int r = 0; r < 8; r++) {
            int row = rg * 8 + r;
            acc[r] = fmaf(sh_hd[row][k], w1, acc[r]);
            acc[r] = fmaf(sh_hn[row][k], w2, acc[r]);
        }
    }

#pragma unroll
    for (int r = 0; r < 8; r++) {
        out[(size_t)(row0 + rg * 8 + r) * D + j] = acc[r];
    }
}

extern "C" void kernel_launch(void* const* d_in, const int* in_sizes, int n_in,
                              void* d_out, int out_size, void* d_ws, size_t ws_size,
                              hipStream_t stream) {
    const float* h_src  = (const float*)d_in[0];
    const float* h_dst  = (const float*)d_in[1];
    const int* src_idx  = (const int*)d_in[2];
    const int* dst_idx  = (const int*)d_in[3];
    const float* W      = (const float*)d_in[4];
    const float* b      = (const float*)d_in[5];
    float* out = (float*)d_out;
    float* deg = (float*)d_ws;   // N_DST floats = 400 KB

    // Zero the accumulators (d_out / d_ws are poisoned with 0xAA before each call).
    hipMemsetAsync(out, 0, (size_t)N_DST * D * sizeof(float), stream);
    hipMemsetAsync(deg, 0, (size_t)N_DST * sizeof(float), stream);

    // Scatter: E*32 threads.
    int scatter_blocks = (N_EDGES * 32) / 256;  // 80000
    sage_scatter<<<scatter_blocks, 256, 0, stream>>>(h_src, src_idx, dst_idx, out, deg);

    // GEMM: one block per 16 rows. 100000/16 = 6250 exactly.
    sage_gemm<<<N_DST / ROWS, 256, 0, stream>>>(h_dst, W, b, deg, out);
}

// Round 2
// 466.225 us; speedup vs baseline: 3.0630x; 3.0630x over previous
//
#include <hip/hip_runtime.h>

#define D 128
#define N_SRC 100000
#define N_DST 100000
#define N_EDGES 640000
#define ROWS 16

#define SCAN_BLK 1024   // elements scanned per block (256 threads x 4)
#define N_SCAN_BLOCKS ((N_DST + SCAN_BLK - 1) / SCAN_BLK)   // 98

// ---- CSR build ----------------------------------------------------------

__global__ __launch_bounds__(256) void hist_kernel(
    const int* __restrict__ dst_idx, int* __restrict__ counts)
{
    int e = blockIdx.x * 256 + threadIdx.x;
    if (e < N_EDGES) atomicAdd(&counts[dst_idx[e]], 1);
}

// Per-block exclusive scan of 1024 counts; emits block total.
__global__ __launch_bounds__(256) void scan_blocks(
    const int* __restrict__ counts, int* __restrict__ row_start,
    int* __restrict__ block_sums)
{
    __shared__ int sh[256];
    const int tid = threadIdx.x;
    const int base = blockIdx.x * SCAN_BLK + tid * 4;
    int v[4];
    int local = 0;
#pragma unroll
    for (int k = 0; k < 4; k++) {
        int idx = base + k;
        v[k] = (idx < N_DST) ? counts[idx] : 0;
        local += v[k];
    }
    sh[tid] = local;
    __syncthreads();
    for (int off = 1; off < 256; off <<= 1) {   // Hillis-Steele inclusive
        int t = (tid >= off) ? sh[tid - off] : 0;
        __syncthreads();
        sh[tid] += t;
        __syncthreads();
    }
    int run = (tid == 0) ? 0 : sh[tid - 1];     // exclusive prefix
    if (tid == 255) block_sums[blockIdx.x] = sh[255];
#pragma unroll
    for (int k = 0; k < 4; k++) {
        int idx = base + k;
        if (idx < N_DST) row_start[idx] = run;
        run += v[k];
    }
}

// Exclusive scan of the 98 block sums (single block).
__global__ __launch_bounds__(128) void scan_top(
    const int* __restrict__ block_sums, int* __restrict__ block_offsets)
{
    __shared__ int sh[128];
    const int tid = threadIdx.x;
    sh[tid] = (tid < N_SCAN_BLOCKS) ? block_sums[tid] : 0;
    __syncthreads();
    for (int off = 1; off < 128; off <<= 1) {
        int t = (tid >= off) ? sh[tid - off] : 0;
        __syncthreads();
        sh[tid] += t;
        __syncthreads();
    }
    if (tid < N_SCAN_BLOCKS) block_offsets[tid] = (tid == 0) ? 0 : sh[tid - 1];
}

// Add block offsets; init the scatter cursor; cap the row_start array.
__global__ __launch_bounds__(256) void add_offsets(
    int* __restrict__ row_start, const int* __restrict__ block_offsets,
    int* __restrict__ cursor)
{
    int i = blockIdx.x * 256 + threadIdx.x;
    if (i < N_DST) {
        int v = row_start[i] + block_offsets[i / SCAN_BLK];
        row_start[i] = v;
        cursor[i] = v;
    }
    if (i == 0) row_start[N_DST] = N_EDGES;
}

// Permute edge source indices into dst-sorted order.
__global__ __launch_bounds__(256) void scatter_perm(
    const int* __restrict__ src_idx, const int* __restrict__ dst_idx,
    int* __restrict__ cursor, int* __restrict__ edge_src)
{
    int e = blockIdx.x * 256 + threadIdx.x;
    if (e < N_EDGES) {
        int d = dst_idx[e];
        int pos = atomicAdd(&cursor[d], 1);
        edge_src[pos] = src_idx[e];
    }
}

// ---- Aggregation: one wave per destination row --------------------------
// Writes the NORMALIZED neighbor mean h_N directly into d_out; no atomics.
__global__ __launch_bounds__(256) void aggregate(
    const float* __restrict__ h_src, const int* __restrict__ row_start,
    const int* __restrict__ edge_src, float* __restrict__ out)
{
    const int wave = threadIdx.x >> 6;
    const int lane = threadIdx.x & 63;
    const int row = blockIdx.x * 4 + wave;
    if (row >= N_DST) return;
    const int start = row_start[row];
    const int end = row_start[row + 1];
    float2 acc = {0.f, 0.f};
    for (int e = start; e < end; e++) {
        int s = edge_src[e];                                 // wave-uniform
        float2 v = ((const float2*)(h_src + (size_t)s * D))[lane];
        acc.x += v.x; acc.y += v.y;
    }
    const float inv = 1.0f / fmaxf((float)(end - start), 1.0f);
    float2 r; r.x = acc.x * inv; r.y = acc.y * inv;
    ((float2*)(out + (size_t)row * D))[lane] = r;
}

// ---- Projection: out[i,:] = b + h_dst[i,:]@W1 + h_N[i,:]@W2 --------------
// One block = 16 rows. Reads its rows' h_N from `out`, then overwrites them.
__global__ __launch_bounds__(256) void sage_gemm(
    const float* __restrict__ h_dst,
    const float* __restrict__ W,     // [256, 128]
    const float* __restrict__ b,     // [128]
    float* __restrict__ out)
{
    __shared__ float sh_hd[ROWS][D];
    __shared__ float sh_hn[ROWS][D];

    const int row0 = blockIdx.x * ROWS;
    const int tid = threadIdx.x;

    for (int i = tid; i < ROWS * D / 4; i += 256) {
        ((float4*)sh_hd)[i] = ((const float4*)(h_dst + (size_t)row0 * D))[i];
        ((float4*)sh_hn)[i] = ((const float4*)(out + (size_t)row0 * D))[i];
    }
    __syncthreads();

    const int j  = tid & 127;
    const int rg = tid >> 7;

    float acc[8];
    const float bj = b[j];
#pragma unroll
    for (int r = 0; r < 8; r++) acc[r] = bj;

    for (int k = 0; k < D; k++) {
        float w1 = W[k * D + j];
        float w2 = W[(D + k) * D + j];
#pragma unroll
        for (int r = 0; r < 8; r++) {
            int row = rg * 8 + r;
            acc[r] = fmaf(sh_hd[row][k], w1, acc[r]);
            acc[r] = fmaf(sh_hn[row][k], w2, acc[r]);
        }
    }

#pragma unroll
    for (int r = 0; r < 8; r++) {
        out[(size_t)(row0 + rg * 8 + r) * D + j] = acc[r];
    }
}

extern "C" void kernel_launch(void* const* d_in, const int* in_sizes, int n_in,
                              void* d_out, int out_size, void* d_ws, size_t ws_size,
                              hipStream_t stream) {
    const float* h_src  = (const float*)d_in[0];
    const float* h_dst  = (const float*)d_in[1];
    const int* src_idx  = (const int*)d_in[2];
    const int* dst_idx  = (const int*)d_in[3];
    const float* W      = (const float*)d_in[4];
    const float* b      = (const float*)d_in[5];
    float* out = (float*)d_out;

    // Workspace layout (ints): ~3.8 MB total
    int* ws_i          = (int*)d_ws;
    int* row_start     = ws_i;                          // N_DST+1
    int* cursor        = row_start + (N_DST + 1);       // N_DST
    int* counts        = cursor + N_DST;                // N_DST
    int* block_sums    = counts + N_DST;                // N_SCAN_BLOCKS
    int* block_offsets = block_sums + N_SCAN_BLOCKS;    // N_SCAN_BLOCKS
    int* edge_src      = block_offsets + N_SCAN_BLOCKS; // N_EDGES

    hipMemsetAsync(counts, 0, (size_t)N_DST * sizeof(int), stream);

    hist_kernel<<<(N_EDGES + 255) / 256, 256, 0, stream>>>(dst_idx, counts);
    scan_blocks<<<N_SCAN_BLOCKS, 256, 0, stream>>>(counts, row_start, block_sums);
    scan_top<<<1, 128, 0, stream>>>(block_sums, block_offsets);
    add_offsets<<<(N_DST + 255) / 256, 256, 0, stream>>>(row_start, block_offsets, cursor);
    scatter_perm<<<(N_EDGES + 255) / 256, 256, 0, stream>>>(src_idx, dst_idx, cursor, edge_src);

    aggregate<<<N_DST / 4, 256, 0, stream>>>(h_src, row_start, edge_src, out);

    sage_gemm<<<N_DST / ROWS, 256, 0, stream>>>(h_dst, W, b, out);
}

// Round 3
// 462.094 us; speedup vs baseline: 3.0904x; 1.0089x over previous
//
#include <hip/hip_runtime.h>

#define D 128
#define N_SRC 100000
#define N_DST 100000
#define N_EDGES 640000

#define SCAN_BLK 1024
#define N_SCAN_BLOCKS ((N_DST + SCAN_BLK - 1) / SCAN_BLK)   // 98

#define BM 128
#define BN 128
#define BK 32

// ---- CSR build ----------------------------------------------------------

__global__ __launch_bounds__(256) void hist_kernel(
    const int* __restrict__ dst_idx, int* __restrict__ counts)
{
    int e = blockIdx.x * 256 + threadIdx.x;
    if (e < N_EDGES) atomicAdd(&counts[dst_idx[e]], 1);
}

__global__ __launch_bounds__(256) void scan_blocks(
    const int* __restrict__ counts, int* __restrict__ row_start,
    int* __restrict__ block_sums)
{
    __shared__ int sh[256];
    const int tid = threadIdx.x;
    const int base = blockIdx.x * SCAN_BLK + tid * 4;
    int v[4];
    int local = 0;
#pragma unroll
    for (int k = 0; k < 4; k++) {
        int idx = base + k;
        v[k] = (idx < N_DST) ? counts[idx] : 0;
        local += v[k];
    }
    sh[tid] = local;
    __syncthreads();
    for (int off = 1; off < 256; off <<= 1) {
        int t = (tid >= off) ? sh[tid - off] : 0;
        __syncthreads();
        sh[tid] += t;
        __syncthreads();
    }
    int run = (tid == 0) ? 0 : sh[tid - 1];
    if (tid == 255) block_sums[blockIdx.x] = sh[255];
#pragma unroll
    for (int k = 0; k < 4; k++) {
        int idx = base + k;
        if (idx < N_DST) row_start[idx] = run;
        run += v[k];
    }
}

__global__ __launch_bounds__(128) void scan_top(
    const int* __restrict__ block_sums, int* __restrict__ block_offsets)
{
    __shared__ int sh[128];
    const int tid = threadIdx.x;
    sh[tid] = (tid < N_SCAN_BLOCKS) ? block_sums[tid] : 0;
    __syncthreads();
    for (int off = 1; off < 128; off <<= 1) {
        int t = (tid >= off) ? sh[tid - off] : 0;
        __syncthreads();
        sh[tid] += t;
        __syncthreads();
    }
    if (tid < N_SCAN_BLOCKS) block_offsets[tid] = (tid == 0) ? 0 : sh[tid - 1];
}

__global__ __launch_bounds__(256) void add_offsets(
    int* __restrict__ row_start, const int* __restrict__ block_offsets,
    int* __restrict__ cursor)
{
    int i = blockIdx.x * 256 + threadIdx.x;
    if (i < N_DST) {
        int v = row_start[i] + block_offsets[i / SCAN_BLK];
        row_start[i] = v;
        cursor[i] = v;
    }
    if (i == 0) row_start[N_DST] = N_EDGES;
}

__global__ __launch_bounds__(256) void scatter_perm(
    const int* __restrict__ src_idx, const int* __restrict__ dst_idx,
    int* __restrict__ cursor, int* __restrict__ edge_src)
{
    int e = blockIdx.x * 256 + threadIdx.x;
    if (e < N_EDGES) {
        int d = dst_idx[e];
        int pos = atomicAdd(&cursor[d], 1);
        edge_src[pos] = src_idx[e];
    }
}

// ---- Aggregation: one wave per destination row --------------------------
// Edge ids are fetched 16-at-a-time and broadcast via shfl so the row
// gathers issue back-to-back (no dependent scalar load per iteration).
__global__ __launch_bounds__(256) void aggregate(
    const float* __restrict__ h_src, const int* __restrict__ row_start,
    const int* __restrict__ edge_src, float* __restrict__ out)
{
    const int wave = threadIdx.x >> 6;
    const int lane = threadIdx.x & 63;
    const int row = blockIdx.x * 4 + wave;
    if (row >= N_DST) return;
    const int start = row_start[row];
    const int deg = row_start[row + 1] - start;
    float2 acc = {0.f, 0.f};
    for (int base = 0; base < deg; base += 16) {
        int n = min(16, deg - base);
        int myid = (lane < n) ? edge_src[start + base + lane] : 0;
        for (int t = 0; t < n; t++) {
            int s = __shfl(myid, t);
            float2 v = ((const float2*)(h_src + (size_t)s * D))[lane];
            acc.x += v.x; acc.y += v.y;
        }
    }
    const float inv = 1.0f / fmaxf((float)deg, 1.0f);
    float2 r; r.x = acc.x * inv; r.y = acc.y * inv;
    ((float2*)(out + (size_t)row * D))[lane] = r;
}

// ---- Projection: register-blocked 128x128 tile, 8x8 micro-tile ----------
// out[i,:] = b + h_dst[i,:] @ W[0:128,:] + h_N[i,:] @ W[128:256,:]
// h_N lives in `out` (written by aggregate); block owns its rows so it can
// read them into LDS then overwrite.
__global__ __launch_bounds__(256, 4) void sage_gemm2(
    const float* __restrict__ h_dst,
    const float* __restrict__ W,     // [256, 128]
    const float* __restrict__ b,     // [128]
    float* __restrict__ out)
{
    __shared__ float sh_a[BK][BM];   // A^T: 16 KB
    __shared__ float sh_b[BK][BN];   // W chunk: 16 KB

    const int tid = threadIdx.x;
    const int row0 = blockIdx.x * BM;
    const int tx = tid & 15;   // column group (8 cols)
    const int ty = tid >> 4;   // row group (8 rows)

    float acc[8][8];
#pragma unroll
    for (int i = 0; i < 8; i++)
#pragma unroll
        for (int j = 0; j < 8; j++) acc[i][j] = 0.f;

    for (int c = 0; c < 8; c++) {   // 8 chunks of BK=32 over K=256
        const float* Asrc = (c < 4) ? h_dst : out;
        const int gk0 = (c < 4) ? c * BK : c * BK - 128;

        // A tile: 128 rows x 32 k -> LDS transposed. 1024 float4, 4/thread.
#pragma unroll
        for (int i = 0; i < 4; i++) {
            int idx = tid + i * 256;
            int r  = idx >> 3;        // row in tile (8 float4 per row)
            int kq = idx & 7;         // which float4 along k
            int grow = row0 + r;
            float4 v = make_float4(0.f, 0.f, 0.f, 0.f);
            if (grow < N_DST)
                v = *(const float4*)(Asrc + (size_t)grow * D + gk0 + kq * 4);
            sh_a[kq * 4 + 0][r] = v.x;
            sh_a[kq * 4 + 1][r] = v.y;
            sh_a[kq * 4 + 2][r] = v.z;
            sh_a[kq * 4 + 3][r] = v.w;
        }
        // B tile: W rows c*32..+31, all 128 cols. 1024 float4, coalesced.
#pragma unroll
        for (int i = 0; i < 4; i++) {
            int idx = tid + i * 256;
            ((float4*)sh_b)[idx] = *(const float4*)(W + (size_t)c * BK * D + idx * 4);
        }
        __syncthreads();

#pragma unroll
        for (int k = 0; k < BK; k++) {
            float af[8], bf[8];
            *(float4*)&af[0] = *(float4*)&sh_a[k][ty * 8];
            *(float4*)&af[4] = *(float4*)&sh_a[k][ty * 8 + 4];
            *(float4*)&bf[0] = *(float4*)&sh_b[k][tx * 8];
            *(float4*)&bf[4] = *(float4*)&sh_b[k][tx * 8 + 4];
#pragma unroll
            for (int i = 0; i < 8; i++)
#pragma unroll
                for (int j = 0; j < 8; j++)
                    acc[i][j] = fmaf(af[i], bf[j], acc[i][j]);
        }
        __syncthreads();
    }

    // Epilogue: add bias, store 8x8 per thread as two float4 per row.
    float bj[8];
    *(float4*)&bj[0] = *(const float4*)&b[tx * 8];
    *(float4*)&bj[4] = *(const float4*)&b[tx * 8 + 4];
#pragma unroll
    for (int i = 0; i < 8; i++) {
        int grow = row0 + ty * 8 + i;
        if (grow < N_DST) {
            float4 v0 = {acc[i][0] + bj[0], acc[i][1] + bj[1],
                         acc[i][2] + bj[2], acc[i][3] + bj[3]};
            float4 v1 = {acc[i][4] + bj[4], acc[i][5] + bj[5],
                         acc[i][6] + bj[6], acc[i][7] + bj[7]};
            *(float4*)(out + (size_t)grow * D + tx * 8) = v0;
            *(float4*)(out + (size_t)grow * D + tx * 8 + 4) = v1;
        }
    }
}

extern "C" void kernel_launch(void* const* d_in, const int* in_sizes, int n_in,
                              void* d_out, int out_size, void* d_ws, size_t ws_size,
                              hipStream_t stream) {
    const float* h_src  = (const float*)d_in[0];
    const float* h_dst  = (const float*)d_in[1];
    const int* src_idx  = (const int*)d_in[2];
    const int* dst_idx  = (const int*)d_in[3];
    const float* W      = (const float*)d_in[4];
    const float* b      = (const float*)d_in[5];
    float* out = (float*)d_out;

    int* ws_i          = (int*)d_ws;
    int* row_start     = ws_i;                          // N_DST+1
    int* cursor        = row_start + (N_DST + 1);       // N_DST
    int* counts        = cursor + N_DST;                // N_DST
    int* block_sums    = counts + N_DST;                // N_SCAN_BLOCKS
    int* block_offsets = block_sums + N_SCAN_BLOCKS;    // N_SCAN_BLOCKS
    int* edge_src      = block_offsets + N_SCAN_BLOCKS; // N_EDGES

    hipMemsetAsync(counts, 0, (size_t)N_DST * sizeof(int), stream);

    hist_kernel<<<(N_EDGES + 255) / 256, 256, 0, stream>>>(dst_idx, counts);
    scan_blocks<<<N_SCAN_BLOCKS, 256, 0, stream>>>(counts, row_start, block_sums);
    scan_top<<<1, 128, 0, stream>>>(block_sums, block_offsets);
    add_offsets<<<(N_DST + 255) / 256, 256, 0, stream>>>(row_start, block_offsets, cursor);
    scatter_perm<<<(N_EDGES + 255) / 256, 256, 0, stream>>>(src_idx, dst_idx, cursor, edge_src);

    aggregate<<<N_DST / 4, 256, 0, stream>>>(h_src, row_start, edge_src, out);

    sage_gemm2<<<(N_DST + BM - 1) / BM, 256, 0, stream>>>(h_dst, W, b, out);
}

// Round 4
// 303.727 us; speedup vs baseline: 4.7018x; 1.5214x over previous
//
#include <hip/hip_runtime.h>

#define D 128
#define N_SRC 100000
#define N_DST 100000
#define N_EDGES 640000

#define SCAN_BLK 1024
#define N_SCAN_BLOCKS ((N_DST + SCAN_BLK - 1) / SCAN_BLK)   // 98

typedef __attribute__((ext_vector_type(8))) short s8v;
typedef __attribute__((ext_vector_type(4))) float f32x4;

__device__ __forceinline__ unsigned short f2bf(float f) {
    unsigned int u = __float_as_uint(f);
    u += 0x7fffu + ((u >> 16) & 1u);   // round-to-nearest-even
    return (unsigned short)(u >> 16);
}

// ---- CSR build ----------------------------------------------------------

__global__ __launch_bounds__(256) void hist_kernel(
    const int* __restrict__ dst_idx, int* __restrict__ counts)
{
    int e = blockIdx.x * 256 + threadIdx.x;
    if (e < N_EDGES) atomicAdd(&counts[dst_idx[e]], 1);
}

__global__ __launch_bounds__(256) void scan_blocks(
    const int* __restrict__ counts, int* __restrict__ row_start,
    int* __restrict__ block_sums)
{
    __shared__ int sh[256];
    const int tid = threadIdx.x;
    const int base = blockIdx.x * SCAN_BLK + tid * 4;
    int v[4];
    int local = 0;
#pragma unroll
    for (int k = 0; k < 4; k++) {
        int idx = base + k;
        v[k] = (idx < N_DST) ? counts[idx] : 0;
        local += v[k];
    }
    sh[tid] = local;
    __syncthreads();
    for (int off = 1; off < 256; off <<= 1) {
        int t = (tid >= off) ? sh[tid - off] : 0;
        __syncthreads();
        sh[tid] += t;
        __syncthreads();
    }
    int run = (tid == 0) ? 0 : sh[tid - 1];
    if (tid == 255) block_sums[blockIdx.x] = sh[255];
#pragma unroll
    for (int k = 0; k < 4; k++) {
        int idx = base + k;
        if (idx < N_DST) row_start[idx] = run;
        run += v[k];
    }
}

__global__ __launch_bounds__(128) void scan_top(
    const int* __restrict__ block_sums, int* __restrict__ block_offsets)
{
    __shared__ int sh[128];
    const int tid = threadIdx.x;
    sh[tid] = (tid < N_SCAN_BLOCKS) ? block_sums[tid] : 0;
    __syncthreads();
    for (int off = 1; off < 128; off <<= 1) {
        int t = (tid >= off) ? sh[tid - off] : 0;
        __syncthreads();
        sh[tid] += t;
        __syncthreads();
    }
    if (tid < N_SCAN_BLOCKS) block_offsets[tid] = (tid == 0) ? 0 : sh[tid - 1];
}

__global__ __launch_bounds__(256) void add_offsets(
    int* __restrict__ row_start, const int* __restrict__ block_offsets,
    int* __restrict__ cursor)
{
    int i = blockIdx.x * 256 + threadIdx.x;
    if (i < N_DST) {
        int v = row_start[i] + block_offsets[i / SCAN_BLK];
        row_start[i] = v;
        cursor[i] = v;
    }
    if (i == 0) row_start[N_DST] = N_EDGES;
}

__global__ __launch_bounds__(256) void scatter_perm(
    const int* __restrict__ src_idx, const int* __restrict__ dst_idx,
    int* __restrict__ cursor, int* __restrict__ edge_src)
{
    int e = blockIdx.x * 256 + threadIdx.x;
    if (e < N_EDGES) {
        int d = dst_idx[e];
        int pos = atomicAdd(&cursor[d], 1);
        edge_src[pos] = src_idx[e];
    }
}

// ---- Cast h_dst into the A buffer (d_out), bytes [0,256) of each row ----
// A layout: row i = 512 B: [h_dst_bf16 (128x2B) | h_N_bf16 (128x2B)] = bf16 K=0..255.
__global__ __launch_bounds__(256) void convert_hdst(
    const float* __restrict__ h_dst, unsigned short* __restrict__ A)
{
    int t = blockIdx.x * 256 + threadIdx.x;   // N_DST*16 threads
    if (t >= N_DST * 16) return;
    int row = t >> 4;
    int cq = t & 15;
    const float* src = h_dst + (size_t)row * D + cq * 8;
    float4 v0 = *(const float4*)(src);
    float4 v1 = *(const float4*)(src + 4);
    unsigned short o[8];
    o[0] = f2bf(v0.x); o[1] = f2bf(v0.y); o[2] = f2bf(v0.z); o[3] = f2bf(v0.w);
    o[4] = f2bf(v1.x); o[5] = f2bf(v1.y); o[6] = f2bf(v1.z); o[7] = f2bf(v1.w);
    // row stride in A is 256 u16 (512 B); h_dst half at offset 0
    *(s8v*)(A + (size_t)row * 256 + cq * 8) = *(s8v*)o;
}

// ---- Pack W into MFMA B-fragment order (bf16) ---------------------------
// Bp[((s*8+t)*64 + lane)*8 + j] = bf16( W[k=s*32+(lane>>4)*8+j][n=t*16+(lane&15)] )
__global__ __launch_bounds__(256) void pack_W(
    const float* __restrict__ W, unsigned short* __restrict__ Bp)
{
    int id = blockIdx.x * 256 + threadIdx.x;   // 32768
    if (id >= 32768) return;
    int j = id & 7;
    int l = (id >> 3) & 63;
    int t = (id >> 9) & 7;
    int s = id >> 12;
    int k = s * 32 + (l >> 4) * 8 + j;
    int n = t * 16 + (l & 15);
    Bp[id] = f2bf(W[k * D + n]);
}

// ---- Aggregation: one wave per destination row, writes bf16 h_N ---------
// Writes the normalized mean as bf16 into bytes [256,512) of each A row.
__global__ __launch_bounds__(256) void aggregate(
    const float* __restrict__ h_src, const int* __restrict__ row_start,
    const int* __restrict__ edge_src, unsigned int* __restrict__ A32)
{
    const int wave = threadIdx.x >> 6;
    const int lane = threadIdx.x & 63;
    const int row = blockIdx.x * 4 + wave;
    if (row >= N_DST) return;
    const int start = row_start[row];
    const int deg = row_start[row + 1] - start;
    float2 acc = {0.f, 0.f};
    for (int base = 0; base < deg; base += 16) {
        int n = min(16, deg - base);
        int myid = (lane < n) ? edge_src[start + base + lane] : 0;
        for (int t = 0; t < n; t++) {
            int s = __shfl(myid, t);
            float2 v = ((const float2*)(h_src + (size_t)s * D))[lane];
            acc.x += v.x; acc.y += v.y;
        }
    }
    const float inv = 1.0f / fmaxf((float)deg, 1.0f);
    unsigned int packed = (unsigned int)f2bf(acc.x * inv)
                        | ((unsigned int)f2bf(acc.y * inv) << 16);
    // row stride 128 u32; h_N half starts at u32 64
    A32[(size_t)row * 128 + 64 + lane] = packed;
}

// ---- Projection via MFMA 16x16x32 bf16 ----------------------------------
// One wave = 16 rows x 128 cols. No LDS, no barriers. A frags straight from
// global (the interleaved buffer in d_out); B frags from packed W (L2-hot).
// Wave reads its own rows then overwrites them with the f32 result.
__global__ __launch_bounds__(256, 4) void mfma_gemm(
    const unsigned short* __restrict__ A,   // [N_DST][256] bf16 (in d_out)
    const unsigned short* __restrict__ Bp,  // packed W fragments
    const float* __restrict__ bias,
    float* __restrict__ out)
{
    const int wave = threadIdx.x >> 6;
    const int lane = threadIdx.x & 63;
    const int row0 = (blockIdx.x * 4 + wave) * 16;
    if (row0 >= N_DST) return;
    const int quad = lane >> 4;
    const int lr = lane & 15;

    f32x4 acc[8];
#pragma unroll
    for (int t = 0; t < 8; t++) acc[t] = (f32x4){0.f, 0.f, 0.f, 0.f};

    const unsigned short* arow = A + (size_t)(row0 + lr) * 256 + quad * 8;

#pragma unroll
    for (int s = 0; s < 8; s++) {
        s8v a = *(const s8v*)(arow + s * 32);
#pragma unroll
        for (int t = 0; t < 8; t++) {
            s8v bf = *(const s8v*)(Bp + (((size_t)(s * 8 + t) * 64 + lane) * 8));
            acc[t] = __builtin_amdgcn_mfma_f32_16x16x32_bf16(a, bf, acc[t], 0, 0, 0);
        }
    }

#pragma unroll
    for (int t = 0; t < 8; t++) {
        float bv = bias[t * 16 + lr];
#pragma unroll
        for (int r = 0; r < 4; r++) {
            int row = row0 + quad * 4 + r;
            out[(size_t)row * D + t * 16 + lr] = acc[t][r] + bv;
        }
    }
}

extern "C" void kernel_launch(void* const* d_in, const int* in_sizes, int n_in,
                              void* d_out, int out_size, void* d_ws, size_t ws_size,
                              hipStream_t stream) {
    const float* h_src  = (const float*)d_in[0];
    const float* h_dst  = (const float*)d_in[1];
    const int* src_idx  = (const int*)d_in[2];
    const int* dst_idx  = (const int*)d_in[3];
    const float* W      = (const float*)d_in[4];
    const float* b      = (const float*)d_in[5];
    float* out = (float*)d_out;

    // Workspace: Bp first (16B-aligned), then CSR int arrays (~3.9 MB total)
    unsigned short* Bp = (unsigned short*)d_ws;         // 32768 u16 = 64 KB
    int* ws_i          = (int*)((char*)d_ws + 65536);
    int* row_start     = ws_i;                          // N_DST+1
    int* cursor        = row_start + (N_DST + 1);       // N_DST
    int* counts        = cursor + N_DST;                // N_DST
    int* block_sums    = counts + N_DST;                // N_SCAN_BLOCKS
    int* block_offsets = block_sums + N_SCAN_BLOCKS;    // N_SCAN_BLOCKS
    int* edge_src      = block_offsets + N_SCAN_BLOCKS; // N_EDGES

    hipMemsetAsync(counts, 0, (size_t)N_DST * sizeof(int), stream);

    hist_kernel<<<(N_EDGES + 255) / 256, 256, 0, stream>>>(dst_idx, counts);
    scan_blocks<<<N_SCAN_BLOCKS, 256, 0, stream>>>(counts, row_start, block_sums);
    scan_top<<<1, 128, 0, stream>>>(block_sums, block_offsets);
    add_offsets<<<(N_DST + 255) / 256, 256, 0, stream>>>(row_start, block_offsets, cursor);
    scatter_perm<<<(N_EDGES + 255) / 256, 256, 0, stream>>>(src_idx, dst_idx, cursor, edge_src);

    convert_hdst<<<(N_DST * 16 + 255) / 256, 256, 0, stream>>>(
        h_dst, (unsigned short*)d_out);
    pack_W<<<128, 256, 0, stream>>>(W, Bp);

    aggregate<<<N_DST / 4, 256, 0, stream>>>(h_src, row_start, edge_src,
                                             (unsigned int*)d_out);

    int gemm_blocks = (N_DST / 16 + 3) / 4;   // 6250 waves -> 1563 blocks
    mfma_gemm<<<gemm_blocks, 256, 0, stream>>>(
        (const unsigned short*)d_out, Bp, b, out);
}

// Round 5
// 281.287 us; speedup vs baseline: 5.0768x; 1.0798x over previous
//
#include <hip/hip_runtime.h>

#define D 128
#define N_SRC 100000
#define N_DST 100000
#define N_EDGES 640000

#define SCAN_BLK 1024
#define N_SCAN_BLOCKS ((N_DST + SCAN_BLK - 1) / SCAN_BLK)   // 98

typedef __attribute__((ext_vector_type(8))) short s8v;
typedef __attribute__((ext_vector_type(4))) float f32x4;

__device__ __forceinline__ unsigned short f2bf(float f) {
    unsigned int u = __float_as_uint(f);
    u += 0x7fffu + ((u >> 16) & 1u);   // round-to-nearest-even
    return (unsigned short)(u >> 16);
}

// ---- CSR build ----------------------------------------------------------

__global__ __launch_bounds__(256) void hist_kernel(
    const int* __restrict__ dst_idx, int* __restrict__ counts)
{
    int e = blockIdx.x * 256 + threadIdx.x;
    if (e < N_EDGES) atomicAdd(&counts[dst_idx[e]], 1);
}

__global__ __launch_bounds__(256) void scan_blocks(
    const int* __restrict__ counts, int* __restrict__ row_start,
    int* __restrict__ block_sums)
{
    __shared__ int sh[256];
    const int tid = threadIdx.x;
    const int base = blockIdx.x * SCAN_BLK + tid * 4;
    int v[4];
    int local = 0;
#pragma unroll
    for (int k = 0; k < 4; k++) {
        int idx = base + k;
        v[k] = (idx < N_DST) ? counts[idx] : 0;
        local += v[k];
    }
    sh[tid] = local;
    __syncthreads();
    for (int off = 1; off < 256; off <<= 1) {
        int t = (tid >= off) ? sh[tid - off] : 0;
        __syncthreads();
        sh[tid] += t;
        __syncthreads();
    }
    int run = (tid == 0) ? 0 : sh[tid - 1];
    if (tid == 255) block_sums[blockIdx.x] = sh[255];
#pragma unroll
    for (int k = 0; k < 4; k++) {
        int idx = base + k;
        if (idx < N_DST) row_start[idx] = run;
        run += v[k];
    }
}

__global__ __launch_bounds__(128) void scan_top(
    const int* __restrict__ block_sums, int* __restrict__ block_offsets)
{
    __shared__ int sh[128];
    const int tid = threadIdx.x;
    sh[tid] = (tid < N_SCAN_BLOCKS) ? block_sums[tid] : 0;
    __syncthreads();
    for (int off = 1; off < 128; off <<= 1) {
        int t = (tid >= off) ? sh[tid - off] : 0;
        __syncthreads();
        sh[tid] += t;
        __syncthreads();
    }
    if (tid < N_SCAN_BLOCKS) block_offsets[tid] = (tid == 0) ? 0 : sh[tid - 1];
}

__global__ __launch_bounds__(256) void add_offsets(
    int* __restrict__ row_start, const int* __restrict__ block_offsets,
    int* __restrict__ cursor)
{
    int i = blockIdx.x * 256 + threadIdx.x;
    if (i < N_DST) {
        int v = row_start[i] + block_offsets[i / SCAN_BLK];
        row_start[i] = v;
        cursor[i] = v;
    }
    if (i == 0) row_start[N_DST] = N_EDGES;
}

__global__ __launch_bounds__(256) void scatter_perm(
    const int* __restrict__ src_idx, const int* __restrict__ dst_idx,
    int* __restrict__ cursor, int* __restrict__ edge_src)
{
    int e = blockIdx.x * 256 + threadIdx.x;
    if (e < N_EDGES) {
        int d = dst_idx[e];
        int pos = atomicAdd(&cursor[d], 1);
        edge_src[pos] = src_idx[e];
    }
}

// ---- Pack W into MFMA B-fragment order (bf16) ---------------------------
// Bp[((s*8+t)*64 + lane)*8 + j] = bf16( W[k=s*32+(lane>>4)*8+j][n=t*16+(lane&15)] )
__global__ __launch_bounds__(256) void pack_W(
    const float* __restrict__ W, unsigned short* __restrict__ Bp)
{
    int id = blockIdx.x * 256 + threadIdx.x;   // 32768
    if (id >= 32768) return;
    int j = id & 7;
    int l = (id >> 3) & 63;
    int t = (id >> 9) & 7;
    int s = id >> 12;
    int k = s * 32 + (l >> 4) * 8 + j;
    int n = t * 16 + (l & 15);
    Bp[id] = f2bf(W[k * D + n]);
}

// ---- Aggregation: one wave per destination row --------------------------
// Fixed-trip batch of 8 gathers per iteration (clamped ids, masked adds) so
// all 8 row-loads are independent and in flight together. Writes the bf16
// mean into u32 words [64,128) of each 512-B d_out row.
__global__ __launch_bounds__(256) void aggregate(
    const float* __restrict__ h_src, const int* __restrict__ row_start,
    const int* __restrict__ edge_src, unsigned int* __restrict__ A32)
{
    const int wave = threadIdx.x >> 6;
    const int lane = threadIdx.x & 63;
    const int row = blockIdx.x * 4 + wave;
    if (row >= N_DST) return;
    const int start = row_start[row];
    const int deg = row_start[row + 1] - start;
    float2 acc = {0.f, 0.f};
    for (int base = 0; base < deg; base += 8) {
        // lanes 0..7 hold the batch's (clamped) edge ids
        int j = base + (lane & 7);
        int myid = edge_src[start + min(j, deg - 1)];
#pragma unroll
        for (int t = 0; t < 8; t++) {
            int s = __shfl(myid, t);
            float2 v = ((const float2*)(h_src + (size_t)s * D))[lane];
            bool ok = (base + t) < deg;
            acc.x += ok ? v.x : 0.f;
            acc.y += ok ? v.y : 0.f;
        }
    }
    const float inv = 1.0f / fmaxf((float)deg, 1.0f);
    unsigned int packed = (unsigned int)f2bf(acc.x * inv)
                        | ((unsigned int)f2bf(acc.y * inv) << 16);
    A32[(size_t)row * 128 + 64 + lane] = packed;
}

// ---- Projection via MFMA 16x16x32 bf16, 32 rows per wave ----------------
// K=0..127 comes from h_dst (f32, converted in-register); K=128..255 from
// the bf16 h_N halves that aggregate wrote into d_out. Each B fragment
// feeds two MFMAs (two 16-row groups). Wave owns its 32 rows: reads h_N,
// then overwrites the full rows with the f32 result.
__global__ __launch_bounds__(256, 4) void mfma_gemm(
    const float* __restrict__ h_dst,
    const unsigned short* __restrict__ A,   // d_out viewed as u16[N_DST][256]
    const unsigned short* __restrict__ Bp,  // packed W fragments (64 KB)
    const float* __restrict__ bias,
    float* __restrict__ out)
{
    const int wave = threadIdx.x >> 6;
    const int lane = threadIdx.x & 63;
    const int row0 = (blockIdx.x * 4 + wave) * 32;
    if (row0 >= N_DST) return;
    const int quad = lane >> 4;
    const int lr = lane & 15;
    const int r0 = row0 + lr;
    const int r1 = row0 + 16 + lr;

    f32x4 acc0[8], acc1[8];
#pragma unroll
    for (int t = 0; t < 8; t++) {
        acc0[t] = (f32x4){0.f, 0.f, 0.f, 0.f};
        acc1[t] = (f32x4){0.f, 0.f, 0.f, 0.f};
    }

    const float* p0 = h_dst + (size_t)r0 * D + quad * 8;
    const float* p1 = h_dst + (size_t)r1 * D + quad * 8;
    const unsigned short* q0 = A + (size_t)r0 * 256 + 128 + quad * 8;
    const unsigned short* q1 = A + (size_t)r1 * 256 + 128 + quad * 8;

    // K = 0..127: h_dst, convert f32 -> bf16 fragments in-register.
#pragma unroll
    for (int s = 0; s < 4; s++) {
        float4 x0 = *(const float4*)(p0 + s * 32);
        float4 y0 = *(const float4*)(p0 + s * 32 + 4);
        float4 x1 = *(const float4*)(p1 + s * 32);
        float4 y1 = *(const float4*)(p1 + s * 32 + 4);
        unsigned short a0u[8], a1u[8];
        a0u[0]=f2bf(x0.x); a0u[1]=f2bf(x0.y); a0u[2]=f2bf(x0.z); a0u[3]=f2bf(x0.w);
        a0u[4]=f2bf(y0.x); a0u[5]=f2bf(y0.y); a0u[6]=f2bf(y0.z); a0u[7]=f2bf(y0.w);
        a1u[0]=f2bf(x1.x); a1u[1]=f2bf(x1.y); a1u[2]=f2bf(x1.z); a1u[3]=f2bf(x1.w);
        a1u[4]=f2bf(y1.x); a1u[5]=f2bf(y1.y); a1u[6]=f2bf(y1.z); a1u[7]=f2bf(y1.w);
        s8v a0 = *(s8v*)a0u;
        s8v a1 = *(s8v*)a1u;
#pragma unroll
        for (int t = 0; t < 8; t++) {
            s8v bf = *(const s8v*)(Bp + ((size_t)(s * 8 + t) * 64 + lane) * 8);
            acc0[t] = __builtin_amdgcn_mfma_f32_16x16x32_bf16(a0, bf, acc0[t], 0, 0, 0);
            acc1[t] = __builtin_amdgcn_mfma_f32_16x16x32_bf16(a1, bf, acc1[t], 0, 0, 0);
        }
    }
    // K = 128..255: bf16 h_N straight from d_out.
#pragma unroll
    for (int s = 4; s < 8; s++) {
        s8v a0 = *(const s8v*)(q0 + (s - 4) * 32);
        s8v a1 = *(const s8v*)(q1 + (s - 4) * 32);
#pragma unroll
        for (int t = 0; t < 8; t++) {
            s8v bf = *(const s8v*)(Bp + ((size_t)(s * 8 + t) * 64 + lane) * 8);
            acc0[t] = __builtin_amdgcn_mfma_f32_16x16x32_bf16(a0, bf, acc0[t], 0, 0, 0);
            acc1[t] = __builtin_amdgcn_mfma_f32_16x16x32_bf16(a1, bf, acc1[t], 0, 0, 0);
        }
    }

#pragma unroll
    for (int t = 0; t < 8; t++) {
        float bv = bias[t * 16 + lr];
#pragma unroll
        for (int r = 0; r < 4; r++) {
            int rowa = row0 + quad * 4 + r;
            int rowb = row0 + 16 + quad * 4 + r;
            out[(size_t)rowa * D + t * 16 + lr] = acc0[t][r] + bv;
            out[(size_t)rowb * D + t * 16 + lr] = acc1[t][r] + bv;
        }
    }
}

extern "C" void kernel_launch(void* const* d_in, const int* in_sizes, int n_in,
                              void* d_out, int out_size, void* d_ws, size_t ws_size,
                              hipStream_t stream) {
    const float* h_src  = (const float*)d_in[0];
    const float* h_dst  = (const float*)d_in[1];
    const int* src_idx  = (const int*)d_in[2];
    const int* dst_idx  = (const int*)d_in[3];
    const float* W      = (const float*)d_in[4];
    const float* b      = (const float*)d_in[5];
    float* out = (float*)d_out;

    // Workspace: Bp first (16B-aligned), then CSR int arrays (~3.9 MB total)
    unsigned short* Bp = (unsigned short*)d_ws;         // 32768 u16 = 64 KB
    int* ws_i          = (int*)((char*)d_ws + 65536);
    int* row_start     = ws_i;                          // N_DST+1
    int* cursor        = row_start + (N_DST + 1);       // N_DST
    int* counts        = cursor + N_DST;                // N_DST
    int* block_sums    = counts + N_DST;                // N_SCAN_BLOCKS
    int* block_offsets = block_sums + N_SCAN_BLOCKS;    // N_SCAN_BLOCKS
    int* edge_src      = block_offsets + N_SCAN_BLOCKS; // N_EDGES

    hipMemsetAsync(counts, 0, (size_t)N_DST * sizeof(int), stream);

    hist_kernel<<<(N_EDGES + 255) / 256, 256, 0, stream>>>(dst_idx, counts);
    scan_blocks<<<N_SCAN_BLOCKS, 256, 0, stream>>>(counts, row_start, block_sums);
    scan_top<<<1, 128, 0, stream>>>(block_sums, block_offsets);
    add_offsets<<<(N_DST + 255) / 256, 256, 0, stream>>>(row_start, block_offsets, cursor);
    scatter_perm<<<(N_EDGES + 255) / 256, 256, 0, stream>>>(src_idx, dst_idx, cursor, edge_src);

    pack_W<<<128, 256, 0, stream>>>(W, Bp);

    aggregate<<<N_DST / 4, 256, 0, stream>>>(h_src, row_start, edge_src,
                                             (unsigned int*)d_out);

    int gemm_blocks = (N_DST / 32 + 3) / 4;   // 3125 waves -> 782 blocks
    mfma_gemm<<<gemm_blocks, 256, 0, stream>>>(
        h_dst, (const unsigned short*)d_out, Bp, b, out);
}